// Round 13
// baseline (88.497 us; speedup 1.0000x reference)
//
#include <hip/hip_runtime.h>
#include <hip/hip_bf16.h>
#include <math.h>

// NoisyTopExpertsPerItemRouter: B=8,S=4096,D=1024,E=64,K=2
#define B_ 8
#define S_ 4096
#define D_ 1024
#define E_ 64
#define NOISE_STD 0.015625f     // max(1/64, 1e-6)
#define INV_NOISE_STD 64.0f
#define OUT_GATES (B_ * S_ * E_)   // 2097152
#define NBLK 512                   // main grid = S_/8 (64 rows per block)

typedef __attribute__((ext_vector_type(8))) short short8;
typedef __attribute__((ext_vector_type(4))) float f32x4;

// workspace layout (float offsets)
// [0 .. 32768): Wg as bf16 [64][1024] (ushort)
#define WS_GW   32768                    // GW[64]
#define WS_BW   32832                    // BW[64]
#define WS_PART 32896                    // part[512][644] per-block records
#define PART_STRIDE 644                  // 512 imp + 64 sgn + 64 cnt + c1 + c2
#define WS_TOT  (WS_PART + NBLK * PART_STRIDE)
#define N_TOT   642

__device__ __forceinline__ float wave_sum64(float v) {
#pragma unroll
  for (int o = 32; o > 0; o >>= 1) v += __shfl_xor(v, o);
  return v;
}

// ---------------- prep: Wg(bf16) = gamma*W, GW/BW reductions, zero totals ---
__global__ void router_prep(const float* __restrict__ W,
                            const float* __restrict__ gamma,
                            const float* __restrict__ beta,
                            float* __restrict__ ws) {
  if (blockIdx.x >= E_) {
    for (int i = threadIdx.x; i < N_TOT; i += 256) ws[WS_TOT + i] = 0.0f;
    return;
  }
  const int e = blockIdx.x;
  unsigned short* wgb = (unsigned short*)ws;
  float gw = 0.0f, bw = 0.0f;
  for (int d = threadIdx.x; d < D_; d += 256) {
    float wv = W[e * D_ + d];
    float pv = gamma[d] * wv;
    union { __hip_bfloat16 h; unsigned short u; } cv;
    cv.h = __float2bfloat16(pv);
    wgb[e * D_ + d] = cv.u;
    gw += __bfloat162float(cv.h);   // sum of ROUNDED values (consistency)
    bw += beta[d] * wv;
  }
  __shared__ float sred[8];
  gw = wave_sum64(gw);
  bw = wave_sum64(bw);
  const int w = threadIdx.x >> 6, lane = threadIdx.x & 63;
  if (lane == 0) { sred[w] = gw; sred[4 + w] = bw; }
  __syncthreads();
  if (threadIdx.x == 0) {
    ws[WS_GW + e] = sred[0] + sred[1] + sred[2] + sred[3];
    ws[WS_BW + e] = sred[4] + sred[5] + sred[6] + sred[7];
  }
}

// ---------------- main: 64-row, 8 waves, B reg-reuse, 34KB LDS (4 blk/CU) ---
// block = 512 thr = 8 waves; owns 64 rows (r: b=r&7, sl=r>>3, s=8*bid+sl).
// Wave w: et=w&3, rh=w>>2 -> rows 32rh..+15 (accA) and +16..+31 (accB), FULL K;
// each B-fragment feeds 2 MFMAs; waves w,w+4 share et in lockstep (L1 dedup).
// LDS is ONLY the 2x staging buffer (+0.8KB): logits/accumulators reuse it
// post-GEMM. Epilogue pm/sgn reduce in-register (sl=w, b=rr+4ep are wave-
// local); imp/cnt via a 640-float LDS accumulator aliasing buf1.
// R12 bug fixed: zero ALL 640 accumulator floats (512-thread grid-stride).
__global__ void __launch_bounds__(512, 8)
router_main(const float* __restrict__ X, const float* __restrict__ noise,
            float* __restrict__ out, float* __restrict__ ws) {
  __shared__ __align__(16) float unbuf[8448];  // 2 x [2][64][33] staging
  __shared__ float svs[64], sv2s[64];
  __shared__ float red16[16];
  float* Lg     = unbuf;          // [64][68] logits (post-GEMM, head of buf0+)
  float* impacc = unbuf + 4352;   // [8][64]  (aliases buf1 tail, post-GEMM)
  float* sgnacc = unbuf + 4864;   // [64]
  float* cntacc = unbuf + 4928;   // [64] -> ends 4992 < 8448

  const int t = threadIdx.x;
  const int w = t >> 6, lane = t & 63;
  const int lrow = lane & 15, kh = lane >> 4;
  const int bid = blockIdx.x;
  const int s0 = bid * 8;

  // staging: thread t -> rows r0=t>>4 and r1=r0+32, dwords c_t..c_t+3 per step
  const int r0 = t >> 4, r1 = r0 + 32, c_t = (t & 15) * 4;
  const int ks_t = c_t >> 5, cw = c_t & 31;
  const int ldso0 = ks_t * 2112 + r0 * 33 + cw;
  const int ldso1 = ldso0 + 32 * 33;
  const float* __restrict__ xstage0 =
      X + ((size_t)(r0 & 7) * S_ + (size_t)(s0 + (r0 >> 3))) * D_ + c_t;
  const float* __restrict__ xstage1 = xstage0 + 4 * D_;   // r1 = r0+32

  // GEMM: wave w -> et = w&3, rh = w>>2; rows rA=32rh+lrow, rB=rA+16
  const int et = w & 3, rh = w >> 2;
  const int rA = 32 * rh + lrow;
  const unsigned short* __restrict__ bp =
      (const unsigned short*)ws + (16 * et + lrow) * D_ + kh * 8;
  const float gwv = ws[WS_GW + 16 * et + lrow];
  const float bwv = ws[WS_BW + 16 * et + lrow];

  // epilogue indices + EARLY noise loads (land during GEMM; oldest in FIFO)
  const int rr_e = lane >> 4, j_e = lane & 15;
  const int re0 = 8 * w + rr_e, re1 = re0 + 4;
  const int be0 = re0 & 7, be1 = re1 & 7;
  const int se = s0 + w;                      // sl = w for both passes
  const float4 nv0 =
      *(const float4*)(noise + ((size_t)be0 * S_ + se) * E_ + 4 * j_e);
  const float4 nv1 =
      *(const float4*)(noise + ((size_t)be1 * S_ + se) * E_ + 4 * j_e);

  // prologue: X regs steps 0,1 (both rows); B ring steps 0,1; stage step 0
  float4 qx0[2], qx1[2];
  short8 qb[2][2];
  qx0[0] = *(const float4*)(xstage0);
  qx1[0] = *(const float4*)(xstage1);
  qx0[1] = *(const float4*)(xstage0 + 64);
  qx1[1] = *(const float4*)(xstage1 + 64);
  qb[0][0] = *(const short8*)(bp);
  qb[0][1] = *(const short8*)(bp + 32);
  qb[1][0] = *(const short8*)(bp + 64);
  qb[1][1] = *(const short8*)(bp + 96);

  float sa0 = 0.0f, sq0 = 0.0f, sa1 = 0.0f, sq1 = 0.0f;
  {
    float4 v = qx0[0];
    unbuf[ldso0 + 0] = v.x; unbuf[ldso0 + 1] = v.y;
    unbuf[ldso0 + 2] = v.z; unbuf[ldso0 + 3] = v.w;
    sa0 += (v.x + v.y) + (v.z + v.w);
    sq0 = fmaf(v.x, v.x, sq0); sq0 = fmaf(v.y, v.y, sq0);
    sq0 = fmaf(v.z, v.z, sq0); sq0 = fmaf(v.w, v.w, sq0);
    v = qx1[0];
    unbuf[ldso1 + 0] = v.x; unbuf[ldso1 + 1] = v.y;
    unbuf[ldso1 + 2] = v.z; unbuf[ldso1 + 3] = v.w;
    sa1 += (v.x + v.y) + (v.z + v.w);
    sq1 = fmaf(v.x, v.x, sq1); sq1 = fmaf(v.y, v.y, sq1);
    sq1 = fmaf(v.z, v.z, sq1); sq1 = fmaf(v.w, v.w, sq1);
  }

  f32x4 accA = {0.f, 0.f, 0.f, 0.f};
  f32x4 accB = {0.f, 0.f, 0.f, 0.f};

#pragma unroll
  for (int s = 0; s < 16; ++s) {
    __syncthreads();                       // buf[s&1] staged
    if (s + 2 < 16) {                      // X for step s+2 (slot s&1 free)
      qx0[s & 1] = *(const float4*)(xstage0 + (s + 2) * 64);
      qx1[s & 1] = *(const float4*)(xstage1 + (s + 2) * 64);
    }
    const float* xbA = unbuf + (s & 1) * 4224 + rA * 33 + kh * 8;
#pragma unroll
    for (int ks = 0; ks < 2; ++ks) {
      float4 a0 = *(const float4*)(xbA + ks * 2112);
      float4 a1 = *(const float4*)(xbA + ks * 2112 + 4);
      float4 b0 = *(const float4*)(xbA + ks * 2112 + 16 * 33);
      float4 b1 = *(const float4*)(xbA + ks * 2112 + 16 * 33 + 4);
      union { short8 s8; __hip_bfloat162 h[4]; } uA, uB;
      uA.h[0] = __float22bfloat162_rn(make_float2(a0.x, a0.y));
      uA.h[1] = __float22bfloat162_rn(make_float2(a0.z, a0.w));
      uA.h[2] = __float22bfloat162_rn(make_float2(a1.x, a1.y));
      uA.h[3] = __float22bfloat162_rn(make_float2(a1.z, a1.w));
      uB.h[0] = __float22bfloat162_rn(make_float2(b0.x, b0.y));
      uB.h[1] = __float22bfloat162_rn(make_float2(b0.z, b0.w));
      uB.h[2] = __float22bfloat162_rn(make_float2(b1.x, b1.y));
      uB.h[3] = __float22bfloat162_rn(make_float2(b1.z, b1.w));
      accA = __builtin_amdgcn_mfma_f32_16x16x32_bf16(uA.s8, qb[s & 1][ks],
                                                     accA, 0, 0, 0);
      accB = __builtin_amdgcn_mfma_f32_16x16x32_bf16(uB.s8, qb[s & 1][ks],
                                                     accB, 0, 0, 0);
    }
    if (s + 2 < 16) {                      // refill B ring slot just consumed
      qb[s & 1][0] = *(const short8*)(bp + (s + 2) * 64);
      qb[s & 1][1] = *(const short8*)(bp + (s + 2) * 64 + 32);
    }
    if (s + 1 < 16) {                      // stage step s+1 (issued at s-1)
      float4 v = qx0[(s + 1) & 1];
      float* d = unbuf + ((s + 1) & 1) * 4224 + ldso0;
      d[0] = v.x; d[1] = v.y; d[2] = v.z; d[3] = v.w;
      sa0 += (v.x + v.y) + (v.z + v.w);
      sq0 = fmaf(v.x, v.x, sq0); sq0 = fmaf(v.y, v.y, sq0);
      sq0 = fmaf(v.z, v.z, sq0); sq0 = fmaf(v.w, v.w, sq0);
      v = qx1[(s + 1) & 1];
      d = unbuf + ((s + 1) & 1) * 4224 + ldso1;
      d[0] = v.x; d[1] = v.y; d[2] = v.z; d[3] = v.w;
      sa1 += (v.x + v.y) + (v.z + v.w);
      sq1 = fmaf(v.x, v.x, sq1); sq1 = fmaf(v.y, v.y, sq1);
      sq1 = fmaf(v.z, v.z, sq1); sq1 = fmaf(v.w, v.w, sq1);
    }
  }

  // LN stats: 16 staging threads per row -> shfl reduce within 16-lane group
  sa0 += __shfl_xor(sa0, 1); sa0 += __shfl_xor(sa0, 2);
  sa0 += __shfl_xor(sa0, 4); sa0 += __shfl_xor(sa0, 8);
  sq0 += __shfl_xor(sq0, 1); sq0 += __shfl_xor(sq0, 2);
  sq0 += __shfl_xor(sq0, 4); sq0 += __shfl_xor(sq0, 8);
  sa1 += __shfl_xor(sa1, 1); sa1 += __shfl_xor(sa1, 2);
  sa1 += __shfl_xor(sa1, 4); sa1 += __shfl_xor(sa1, 8);
  sq1 += __shfl_xor(sq1, 1); sq1 += __shfl_xor(sq1, 2);
  sq1 += __shfl_xor(sq1, 4); sq1 += __shfl_xor(sq1, 8);
  if ((t & 15) == 0) {
    svs[r0] = sa0; sv2s[r0] = sq0;
    svs[r1] = sa1; sv2s[r1] = sq1;
  }
  __syncthreads();   // all GEMM LDS reads done; unbuf reusable

  // zero ALL 640 accumulator floats (R12 bug: t<640 with 512 threads missed
  // sgnacc/cntacc -> stale staging data corrupted gshard)
  for (int i = t; i < 640; i += 512) unbuf[4352 + i] = 0.0f;
  // logits: C/D layout col=lane&15, row=(lane>>4)*4+i  [m89-verified]
#pragma unroll
  for (int i = 0; i < 4; i++) {
    const int rlA = 32 * rh + kh * 4 + i;
    const int rlB = rlA + 16;
    float muA = svs[rlA] * (1.0f / (float)D_);
    float vrA = sv2s[rlA] * (1.0f / (float)D_) - muA * muA;
    float rsA = rsqrtf(vrA + 1e-5f);
    Lg[rlA * 68 + 16 * et + lrow] = rsA * (accA[i] - muA * gwv) + bwv;
    float muB = svs[rlB] * (1.0f / (float)D_);
    float vrB = sv2s[rlB] * (1.0f / (float)D_) - muB * muB;
    float rsB = rsqrtf(vrB + 1e-5f);
    Lg[rlB * 68 + 16 * et + lrow] = rsB * (accB[i] - muB * gwv) + bwv;
  }
  __syncthreads();

  // ---- epilogue: 8 waves x 2 passes; wave w rows 8w..8w+7 (sl = w) ----
  float gn0 = 0.f, gn1 = 0.f, gn2 = 0.f, gn3 = 0.f;   // noisy-gate sums
  float p0 = 0.f, p1 = 0.f, p2 = 0.f, p3 = 0.f;       // p sums (over b)
#pragma unroll
  for (int ep = 0; ep < 2; ++ep) {
    const int r = ep ? re1 : re0;
    const int b = ep ? be1 : be0;
    const float4 nv = ep ? nv1 : nv0;
    const int j = j_e;
    float4 lv = *(const float4*)(Lg + r * 68 + 4 * j);
    float ln0 = fmaf(NOISE_STD, nv.x, lv.x);
    float ln1 = fmaf(NOISE_STD, nv.y, lv.y);
    float ln2 = fmaf(NOISE_STD, nv.z, lv.z);
    float ln3 = fmaf(NOISE_STD, nv.w, lv.w);

    // combined max+secondmax of noisy logits (m1 also shifts clean softmax)
    float m1 = ln0, m2 = -INFINITY;
    m2 = fmaxf(m2, fminf(m1, ln1)); m1 = fmaxf(m1, ln1);
    m2 = fmaxf(m2, fminf(m1, ln2)); m1 = fmaxf(m1, ln2);
    m2 = fmaxf(m2, fminf(m1, ln3)); m1 = fmaxf(m1, ln3);
#pragma unroll
    for (int o = 1; o <= 8; o <<= 1) {
      float o1 = __shfl_xor(m1, o), o2 = __shfl_xor(m2, o);
      m2 = fmaxf(fmaxf(m2, o2), fminf(m1, o1));
      m1 = fmaxf(m1, o1);
    }
    float ec0 = __expf(lv.x - m1), ec1 = __expf(lv.y - m1);
    float ec2 = __expf(lv.z - m1), ec3 = __expf(lv.w - m1);
    float en0 = __expf(ln0 - m1), en1 = __expf(ln1 - m1);
    float en2 = __expf(ln2 - m1), en3 = __expf(ln3 - m1);
    float sg = (ec0 + ec1) + (ec2 + ec3);
    float sn = (en0 + en1) + (en2 + en3);
#pragma unroll
    for (int o = 1; o <= 8; o <<= 1) {
      sg += __shfl_xor(sg, o);
      sn += __shfl_xor(sn, o);
    }
    const float rg_ = 1.0f / sg, rn_ = 1.0f / sn;
    float4 gnv = { en0 * rn_, en1 * rn_, en2 * rn_, en3 * rn_ };
    float z0 = fminf(fmaxf((m2 - lv.x) * INV_NOISE_STD, -10.f), 10.f);
    float z1 = fminf(fmaxf((m2 - lv.y) * INV_NOISE_STD, -10.f), 10.f);
    float z2 = fminf(fmaxf((m2 - lv.z) * INV_NOISE_STD, -10.f), 10.f);
    float z3 = fminf(fmaxf((m2 - lv.w) * INV_NOISE_STD, -10.f), 10.f);

    *(float4*)(out + ((size_t)b * S_ + se) * E_ + 4 * j) = gnv;

    // clean-gate (importance) accumulation per (b,e): cross-wave -> LDS
    atomicAdd(&impacc[b * 64 + 4 * j + 0], ec0 * rg_);
    atomicAdd(&impacc[b * 64 + 4 * j + 1], ec1 * rg_);
    atomicAdd(&impacc[b * 64 + 4 * j + 2], ec2 * rg_);
    atomicAdd(&impacc[b * 64 + 4 * j + 3], ec3 * rg_);
    // noisy-gate sums and p sums: wave-local -> registers
    gn0 += gnv.x; gn1 += gnv.y; gn2 += gnv.z; gn3 += gnv.w;
    p0 += 0.5f * (1.0f + erff(z0 * 0.70710678118654752f));
    p1 += 0.5f * (1.0f + erff(z1 * 0.70710678118654752f));
    p2 += 0.5f * (1.0f + erff(z2 * 0.70710678118654752f));
    p3 += 0.5f * (1.0f + erff(z3 * 0.70710678118654752f));
    // top-1 count via equality (ties vanishingly rare; softmax is monotone)
    if (ln0 == m1) atomicAdd(&cntacc[4 * j + 0], 1.0f);
    if (ln1 == m1) atomicAdd(&cntacc[4 * j + 1], 1.0f);
    if (ln2 == m1) atomicAdd(&cntacc[4 * j + 2], 1.0f);
    if (ln3 == m1) atomicAdd(&cntacc[4 * j + 3], 1.0f);
  }
  // sum over the 4 rr-groups (lanes rr=0..3) -> P(sl=w, e) and gn-sums
  gn0 += __shfl_xor(gn0, 16); gn0 += __shfl_xor(gn0, 32);
  gn1 += __shfl_xor(gn1, 16); gn1 += __shfl_xor(gn1, 32);
  gn2 += __shfl_xor(gn2, 16); gn2 += __shfl_xor(gn2, 32);
  gn3 += __shfl_xor(gn3, 16); gn3 += __shfl_xor(gn3, 32);
  p0 += __shfl_xor(p0, 16); p0 += __shfl_xor(p0, 32);
  p1 += __shfl_xor(p1, 16); p1 += __shfl_xor(p1, 32);
  p2 += __shfl_xor(p2, 16); p2 += __shfl_xor(p2, 32);
  p3 += __shfl_xor(p3, 16); p3 += __shfl_xor(p3, 32);
  if (lane < 16) {
    atomicAdd(&sgnacc[4 * j_e + 0], gn0);
    atomicAdd(&sgnacc[4 * j_e + 1], gn1);
    atomicAdd(&sgnacc[4 * j_e + 2], gn2);
    atomicAdd(&sgnacc[4 * j_e + 3], gn3);
  }
  // pm stats for this wave's sl: c1 = sum_e P/8, c2 = sum_e (P/8)^2
  float s1 = ((p0 + p1) + (p2 + p3)) * 0.125f;
  float s2 = ((p0 * p0 + p1 * p1) + (p2 * p2 + p3 * p3)) * (1.0f / 64.0f);
#pragma unroll
  for (int o = 1; o <= 8; o <<= 1) {
    s1 += __shfl_xor(s1, o);
    s2 += __shfl_xor(s2, o);
  }
  if (lane == 0) { red16[2 * w] = s1; red16[2 * w + 1] = s2; }
  __syncthreads();

  // ---- phase 2: write PLAIN per-block record (no global atomics) ----
  float* prt = ws + WS_PART + (size_t)bid * PART_STRIDE;
  prt[t] = impacc[t];
  if (t < 64) prt[512 + t] = sgnacc[t];
  else if (t < 128) prt[576 + (t - 64)] = cntacc[t - 64];
  if (t == 0) {
    float c1 = 0.0f, c2 = 0.0f;
#pragma unroll
    for (int i = 0; i < 8; i++) { c1 += red16[2 * i]; c2 += red16[2 * i + 1]; }
    prt[640] = c1;
    prt[641] = c2;
  }
}

// ---------------- reduce: 16 blocks x 32 records, deep unroll ---------------
__global__ void router_reduce(float* __restrict__ ws) {
  const int t = threadIdx.x;
  if (t >= N_TOT) return;
  const int base = blockIdx.x * 32;
  const float* p = ws + WS_PART + (size_t)base * PART_STRIDE + t;
  float acc = 0.0f;
#pragma unroll 8
  for (int i = 0; i < 32; ++i) acc += p[(size_t)i * PART_STRIDE];
  atomicAdd(&ws[WS_TOT + t], acc);
}

// ---------------- finalize: 3 scalar losses from totals ---------------------
__global__ void router_final(const float* __restrict__ ws, float* __restrict__ out) {
  const int lane = threadIdx.x;  // 64 threads = 1 wave
  const float* tot = ws + WS_TOT;
  float impsum = 0.0f;
  for (int b = 0; b < B_; ++b) {
    float v = tot[b * 64 + lane];
    float sfull = wave_sum64(v);
    float mean = sfull * (1.0f / 64.0f);
    float d = v - mean;
    float ss = wave_sum64(d * d);
    impsum += (ss / 63.0f) / (mean * mean);
  }
  float importance = impsum * (1.0f / (float)B_);

  const float N = (float)(S_ * E_);
  float meanp = tot[640] / N;
  float varp = tot[641] / N - meanp * meanp;
  float load = varp / (meanp * meanp);

  const float inv_rows = 1.0f / (float)(B_ * S_);
  float te = (tot[576 + lane] * inv_rows) * (tot[512 + lane] * inv_rows);
  float gs = wave_sum64(te) * (float)E_;

  if (lane == 0) {
    out[OUT_GATES + 0] = importance + load;  // aux (GSHARD_W = 0)
    out[OUT_GATES + 1] = gs;
    out[OUT_GATES + 2] = importance;
    out[OUT_GATES + 3] = load;
  }
}

extern "C" void kernel_launch(void* const* d_in, const int* in_sizes, int n_in,
                              void* d_out, int out_size, void* d_ws, size_t ws_size,
                              hipStream_t stream) {
  (void)in_sizes; (void)n_in; (void)out_size; (void)ws_size;
  const float* X     = (const float*)d_in[0];
  const float* noise = (const float*)d_in[1];
  const float* gamma = (const float*)d_in[2];
  const float* beta  = (const float*)d_in[3];
  const float* W     = (const float*)d_in[4];
  float* out = (float*)d_out;
  float* ws  = (float*)d_ws;

  router_prep<<<dim3(E_ + 1), dim3(256), 0, stream>>>(W, gamma, beta, ws);
  router_main<<<dim3(NBLK), dim3(512), 0, stream>>>(X, noise, out, ws);
  router_reduce<<<dim3(16), dim3(704), 0, stream>>>(ws);
  router_final<<<dim3(1), dim3(64), 0, stream>>>(ws, out);
}

// Round 14
// 77.917 us; speedup vs baseline: 1.1358x; 1.1358x over previous
//
#include <hip/hip_runtime.h>
#include <hip/hip_bf16.h>
#include <math.h>

// NoisyTopExpertsPerItemRouter: B=8,S=4096,D=1024,E=64,K=2
#define B_ 8
#define S_ 4096
#define D_ 1024
#define E_ 64
#define NOISE_STD 0.015625f     // max(1/64, 1e-6)
#define INV_NOISE_STD 64.0f
#define OUT_GATES (B_ * S_ * E_)   // 2097152
#define NBLK 1024                  // main grid = S_/4 (32 rows/block, 4 blk/CU)

typedef __attribute__((ext_vector_type(8))) short short8;
typedef __attribute__((ext_vector_type(4))) float f32x4;

// workspace layout (float offsets)
// [0 .. 32768): Wg as bf16 [64][1024] (ushort)
#define WS_GW   32768                    // GW[64]
#define WS_BW   32832                    // BW[64]
#define WS_PART 32896                    // part[1024][644] per-block records
#define PART_STRIDE 644                  // 512 imp + 64 sgn + 64 cnt + c1 + c2
#define WS_TOT  (WS_PART + NBLK * PART_STRIDE)
#define N_TOT   642

__device__ __forceinline__ float wave_sum64(float v) {
#pragma unroll
  for (int o = 32; o > 0; o >>= 1) v += __shfl_xor(v, o);
  return v;
}

// ---------------- prep: Wg(bf16) = gamma*W, GW/BW reductions, zero totals ---
__global__ void router_prep(const float* __restrict__ W,
                            const float* __restrict__ gamma,
                            const float* __restrict__ beta,
                            float* __restrict__ ws) {
  if (blockIdx.x >= E_) {
    for (int i = threadIdx.x; i < N_TOT; i += 256) ws[WS_TOT + i] = 0.0f;
    return;
  }
  const int e = blockIdx.x;
  unsigned short* wgb = (unsigned short*)ws;
  float gw = 0.0f, bw = 0.0f;
  for (int d = threadIdx.x; d < D_; d += 256) {
    float wv = W[e * D_ + d];
    float pv = gamma[d] * wv;
    union { __hip_bfloat16 h; unsigned short u; } cv;
    cv.h = __float2bfloat16(pv);
    wgb[e * D_ + d] = cv.u;
    gw += __bfloat162float(cv.h);   // sum of ROUNDED values (consistency)
    bw += beta[d] * wv;
  }
  __shared__ float sred[8];
  gw = wave_sum64(gw);
  bw = wave_sum64(bw);
  const int w = threadIdx.x >> 6, lane = threadIdx.x & 63;
  if (lane == 0) { sred[w] = gw; sred[4 + w] = bw; }
  __syncthreads();
  if (threadIdx.x == 0) {
    ws[WS_GW + e] = sred[0] + sred[1] + sred[2] + sred[3];
    ws[WS_BW + e] = sred[4] + sred[5] + sred[6] + sred[7];
  }
}

// ---------------- main: R9 geometry (1024 blk x 8 waves), K-step 128 --------
// block = 512 thr = 8 waves; owns 32 rows (r: b=r&7, sl=r>>3, s=4*bid+sl).
// Wave w: rg=w>>2 (rows 16rg..16rg+15), et=w&3 (experts 16et..+15), FULL K.
// K: 8 steps of 128. X tile [4 ksub][32][33] per buffer (dbuf), staged 2
// float4/thread/step. qx ring depth2; qb ring depth2 x 4 short8 -> all
// consumer waits COUNTED vmcnt. 8 barriers/K-loop (vs R9's 16).
// Post-GEMM: Lg/gcl/gnl/pl alias the staging buffer (all GEMM reads complete
// at the post-loop barrier). Epilogue+phase2 = R9 verbatim.
__global__ void __launch_bounds__(512, 4)
router_main(const float* __restrict__ X, const float* __restrict__ noise,
            float* __restrict__ out, float* __restrict__ ws) {
  __shared__ __align__(16) float unbuf[8448];  // 2 bufs x [4][32][33]
  __shared__ float svs[32], sv2s[32];
  __shared__ float cntl[64];
  __shared__ float red8[16];
  float* gcl = unbuf;          // [32][68] clean gates   (post-GEMM alias)
  float* gnl = unbuf + 2176;   // [32][68] noisy gates
  float* Lg  = unbuf + 4352;   // [32][68] logits
  float* pl  = Lg;             // per-lane read-then-write -> safe alias

  const int t = threadIdx.x;
  const int w = t >> 6, lane = t & 63;
  const int lrow = lane & 15, kh = lane >> 4;
  const int bid = blockIdx.x;
  const int s0 = bid * 4;

  // staging: thread t -> row r_t=t>>4, dwords c8..c8+7 of each 128-dword step
  const int r_t = t >> 4, c8 = (t & 15) * 8;
  const int ksub_t = c8 >> 5, cw = c8 & 31;
  const int ldso = ksub_t * 1056 + r_t * 33 + cw;
  const float* __restrict__ xstage =
      X + ((size_t)(r_t & 7) * S_ + (size_t)(s0 + (r_t >> 3))) * D_ + c8;

  // GEMM: wave w -> rg = w>>2, et = w&3
  const int rg = w >> 2, et = w & 3;
  const unsigned short* __restrict__ bp =
      (const unsigned short*)ws + (16 * et + lrow) * D_ + kh * 8;
  const float gwv = ws[WS_GW + 16 * et + lrow];
  const float bwv = ws[WS_BW + 16 * et + lrow];

  // epilogue indices + EARLY noise load (lands during GEMM)
  const int rr_e = lane >> 4, j_e = lane & 15;
  const int r_e = w * 4 + rr_e;                 // [0,32)
  const int b_e = r_e & 7, sl_e = r_e >> 3;
  const int s_e = s0 + sl_e;
  const float4 nv =
      *(const float4*)(noise + ((size_t)b_e * S_ + s_e) * E_ + 4 * j_e);

  // prologue: X regs steps 0,1; B ring steps 0,1; stage step 0 (+stats)
  float4 qx[2][2];
  short8 qb[2][4];
  qx[0][0] = *(const float4*)(xstage);
  qx[0][1] = *(const float4*)(xstage + 4);
  qx[1][0] = *(const float4*)(xstage + 128);
  qx[1][1] = *(const float4*)(xstage + 132);
#pragma unroll
  for (int p = 0; p < 2; p++)
#pragma unroll
    for (int ks = 0; ks < 4; ks++)
      qb[p][ks] = *(const short8*)(bp + p * 128 + ks * 32);

  float ssv = 0.0f, ssv2 = 0.0f;
#pragma unroll
  for (int h = 0; h < 2; h++) {
    float4 v = qx[0][h];
    float* d = unbuf + ldso + 4 * h;
    d[0] = v.x; d[1] = v.y; d[2] = v.z; d[3] = v.w;
    ssv += (v.x + v.y) + (v.z + v.w);
    ssv2 = fmaf(v.x, v.x, ssv2); ssv2 = fmaf(v.y, v.y, ssv2);
    ssv2 = fmaf(v.z, v.z, ssv2); ssv2 = fmaf(v.w, v.w, ssv2);
  }

  f32x4 acc = {0.f, 0.f, 0.f, 0.f};

#pragma unroll
  for (int s = 0; s < 8; ++s) {
    __syncthreads();                       // buf[s&1] staged
    if (s + 2 < 8) {                       // X for step s+2 (slot s&1 free)
      qx[s & 1][0] = *(const float4*)(xstage + (s + 2) * 128);
      qx[s & 1][1] = *(const float4*)(xstage + (s + 2) * 128 + 4);
    }
    const float* xb = unbuf + (s & 1) * 4224 + (16 * rg + lrow) * 33 + kh * 8;
#pragma unroll
    for (int ks = 0; ks < 4; ++ks) {
      float4 a0 = *(const float4*)(xb + ks * 1056);
      float4 a1 = *(const float4*)(xb + ks * 1056 + 4);
      union { short8 s8; __hip_bfloat162 h[4]; } u;
      u.h[0] = __float22bfloat162_rn(make_float2(a0.x, a0.y));
      u.h[1] = __float22bfloat162_rn(make_float2(a0.z, a0.w));
      u.h[2] = __float22bfloat162_rn(make_float2(a1.x, a1.y));
      u.h[3] = __float22bfloat162_rn(make_float2(a1.z, a1.w));
      acc = __builtin_amdgcn_mfma_f32_16x16x32_bf16(u.s8, qb[s & 1][ks],
                                                    acc, 0, 0, 0);
    }
    if (s + 2 < 8) {                       // refill B ring slot just consumed
#pragma unroll
      for (int ks = 0; ks < 4; ++ks)
        qb[s & 1][ks] = *(const short8*)(bp + (s + 2) * 128 + ks * 32);
    }
    if (s + 1 < 8) {                       // stage step s+1 (issued at s-1)
#pragma unroll
      for (int h = 0; h < 2; h++) {
        float4 v = qx[(s + 1) & 1][h];
        float* d = unbuf + ((s + 1) & 1) * 4224 + ldso + 4 * h;
        d[0] = v.x; d[1] = v.y; d[2] = v.z; d[3] = v.w;
        ssv += (v.x + v.y) + (v.z + v.w);
        ssv2 = fmaf(v.x, v.x, ssv2); ssv2 = fmaf(v.y, v.y, ssv2);
        ssv2 = fmaf(v.z, v.z, ssv2); ssv2 = fmaf(v.w, v.w, ssv2);
      }
    }
  }

  // LN stats: 16 staging threads per row -> shfl reduce within 16-lane group
  ssv  += __shfl_xor(ssv, 1);  ssv  += __shfl_xor(ssv, 2);
  ssv  += __shfl_xor(ssv, 4);  ssv  += __shfl_xor(ssv, 8);
  ssv2 += __shfl_xor(ssv2, 1); ssv2 += __shfl_xor(ssv2, 2);
  ssv2 += __shfl_xor(ssv2, 4); ssv2 += __shfl_xor(ssv2, 8);
  if ((t & 15) == 0) { svs[r_t] = ssv; sv2s[r_t] = ssv2; }
  if (t < 64) cntl[t] = 0.0f;
  __syncthreads();   // all GEMM LDS reads done; unbuf fully reusable

  // logits: C/D layout col=lane&15, row=(lane>>4)*4+i  [m89-verified]
#pragma unroll
  for (int i = 0; i < 4; i++) {
    const int rloc = 16 * rg + kh * 4 + i;
    const float mui = svs[rloc] * (1.0f / (float)D_);
    const float var = sv2s[rloc] * (1.0f / (float)D_) - mui * mui;
    const float rsi = rsqrtf(var + 1e-5f);
    Lg[rloc * 68 + 16 * et + lrow] = rsi * (acc[i] - mui * gwv) + bwv;
  }
  __syncthreads();

  // ---- epilogue: 8 waves; wave w rows 4w..4w+3; lane=(rr,j), 4 experts ----
  {
    const int r = r_e, b = b_e, s = s_e, j = j_e;
    float4 lv = *(const float4*)(Lg + r * 68 + 4 * j);
    float ln0 = fmaf(NOISE_STD, nv.x, lv.x);
    float ln1 = fmaf(NOISE_STD, nv.y, lv.y);
    float ln2 = fmaf(NOISE_STD, nv.z, lv.z);
    float ln3 = fmaf(NOISE_STD, nv.w, lv.w);

    // combined max+secondmax of noisy logits (m1 also shifts clean softmax)
    float m1 = ln0, m2 = -INFINITY;
    m2 = fmaxf(m2, fminf(m1, ln1)); m1 = fmaxf(m1, ln1);
    m2 = fmaxf(m2, fminf(m1, ln2)); m1 = fmaxf(m1, ln2);
    m2 = fmaxf(m2, fminf(m1, ln3)); m1 = fmaxf(m1, ln3);
#pragma unroll
    for (int o = 1; o <= 8; o <<= 1) {
      float o1 = __shfl_xor(m1, o), o2 = __shfl_xor(m2, o);
      m2 = fmaxf(fmaxf(m2, o2), fminf(m1, o1));
      m1 = fmaxf(m1, o1);
    }
    float ec0 = __expf(lv.x - m1), ec1 = __expf(lv.y - m1);
    float ec2 = __expf(lv.z - m1), ec3 = __expf(lv.w - m1);
    float en0 = __expf(ln0 - m1), en1 = __expf(ln1 - m1);
    float en2 = __expf(ln2 - m1), en3 = __expf(ln3 - m1);
    float sg = (ec0 + ec1) + (ec2 + ec3);
    float sn = (en0 + en1) + (en2 + en3);
#pragma unroll
    for (int o = 1; o <= 8; o <<= 1) {
      sg += __shfl_xor(sg, o);
      sn += __shfl_xor(sn, o);
    }
    const float rg_ = 1.0f / sg, rn_ = 1.0f / sn;
    float4 gnv = { en0 * rn_, en1 * rn_, en2 * rn_, en3 * rn_ };
    float4 gcv = { ec0 * rg_, ec1 * rg_, ec2 * rg_, ec3 * rg_ };
    float z0 = fminf(fmaxf((m2 - lv.x) * INV_NOISE_STD, -10.f), 10.f);
    float z1 = fminf(fmaxf((m2 - lv.y) * INV_NOISE_STD, -10.f), 10.f);
    float z2 = fminf(fmaxf((m2 - lv.z) * INV_NOISE_STD, -10.f), 10.f);
    float z3 = fminf(fmaxf((m2 - lv.w) * INV_NOISE_STD, -10.f), 10.f);
    float4 pv = { 0.5f * (1.0f + erff(z0 * 0.70710678118654752f)),
                  0.5f * (1.0f + erff(z1 * 0.70710678118654752f)),
                  0.5f * (1.0f + erff(z2 * 0.70710678118654752f)),
                  0.5f * (1.0f + erff(z3 * 0.70710678118654752f)) };

    *(float4*)(out + ((size_t)b * S_ + s) * E_ + 4 * j) = gnv;
    *(float4*)(gnl + r * 68 + 4 * j) = gnv;
    *(float4*)(gcl + r * 68 + 4 * j) = gcv;
    *(float4*)(pl  + r * 68 + 4 * j) = pv;
    // top-1 count via equality (ties vanishingly rare; softmax is monotone)
    if (ln0 == m1) atomicAdd(&cntl[4 * j + 0], 1.0f);
    if (ln1 == m1) atomicAdd(&cntl[4 * j + 1], 1.0f);
    if (ln2 == m1) atomicAdd(&cntl[4 * j + 2], 1.0f);
    if (ln3 == m1) atomicAdd(&cntl[4 * j + 3], 1.0f);
  }
  __syncthreads();

  // ---- phase 2: block reductions -> PLAIN per-block record (no atomics) ----
  float* prt = ws + WS_PART + (size_t)bid * PART_STRIDE;
  {
    // importance: thread t -> (b = t>>6, e = t&63), sum over 4 sl
    const int b0i = t >> 6, e0i = t & 63;
    float v = 0.0f;
#pragma unroll
    for (int sl = 0; sl < 4; sl++) v += gcl[(sl * 8 + b0i) * 68 + e0i];
    prt[t] = v;
  }
  if (t < 64) {
    float sgn = 0.0f;
#pragma unroll
    for (int r = 0; r < 32; r++) sgn += gnl[r * 68 + t];
    prt[512 + t] = sgn;
  } else if (t < 128) {
    prt[576 + (t - 64)] = cntl[t - 64];
  } else if (t < 384) {
    const int idx = t - 128;            // [0,256): slc = idx>>6, e = idx&63
    const int slc = idx >> 6, e = idx & 63;
    float P = 0.0f;
#pragma unroll
    for (int b = 0; b < 8; b++) P += pl[(slc * 8 + b) * 68 + e];
    float c1 = P * 0.125f;
    float c2 = c1 * c1;
    c1 = wave_sum64(c1);
    c2 = wave_sum64(c2);
    if (lane == 0) { red8[(w - 2) * 2] = c1; red8[(w - 2) * 2 + 1] = c2; }
  }
  __syncthreads();
  if (t == 0) {
    prt[640] = (red8[0] + red8[2]) + (red8[4] + red8[6]);
    prt[641] = (red8[1] + red8[3]) + (red8[5] + red8[7]);
  }
}

// ---------------- reduce: 32 blocks x 32 records, deep unroll ---------------
__global__ void router_reduce(float* __restrict__ ws) {
  const int t = threadIdx.x;
  if (t >= N_TOT) return;
  const int base = blockIdx.x * 32;
  const float* p = ws + WS_PART + (size_t)base * PART_STRIDE + t;
  float acc = 0.0f;
#pragma unroll 8
  for (int i = 0; i < 32; ++i) acc += p[(size_t)i * PART_STRIDE];
  atomicAdd(&ws[WS_TOT + t], acc);
}

// ---------------- finalize: 3 scalar losses from totals ---------------------
__global__ void router_final(const float* __restrict__ ws, float* __restrict__ out) {
  const int lane = threadIdx.x;  // 64 threads = 1 wave
  const float* tot = ws + WS_TOT;
  float impsum = 0.0f;
  for (int b = 0; b < B_; ++b) {
    float v = tot[b * 64 + lane];
    float sfull = wave_sum64(v);
    float mean = sfull * (1.0f / 64.0f);
    float d = v - mean;
    float ss = wave_sum64(d * d);
    impsum += (ss / 63.0f) / (mean * mean);
  }
  float importance = impsum * (1.0f / (float)B_);

  const float N = (float)(S_ * E_);
  float meanp = tot[640] / N;
  float varp = tot[641] / N - meanp * meanp;
  float load = varp / (meanp * meanp);

  const float inv_rows = 1.0f / (float)(B_ * S_);
  float te = (tot[576 + lane] * inv_rows) * (tot[512 + lane] * inv_rows);
  float gs = wave_sum64(te) * (float)E_;

  if (lane == 0) {
    out[OUT_GATES + 0] = importance + load;  // aux (GSHARD_W = 0)
    out[OUT_GATES + 1] = gs;
    out[OUT_GATES + 2] = importance;
    out[OUT_GATES + 3] = load;
  }
}

extern "C" void kernel_launch(void* const* d_in, const int* in_sizes, int n_in,
                              void* d_out, int out_size, void* d_ws, size_t ws_size,
                              hipStream_t stream) {
  (void)in_sizes; (void)n_in; (void)out_size; (void)ws_size;
  const float* X     = (const float*)d_in[0];
  const float* noise = (const float*)d_in[1];
  const float* gamma = (const float*)d_in[2];
  const float* beta  = (const float*)d_in[3];
  const float* W     = (const float*)d_in[4];
  float* out = (float*)d_out;
  float* ws  = (float*)d_ws;

  router_prep<<<dim3(E_ + 1), dim3(256), 0, stream>>>(W, gamma, beta, ws);
  router_main<<<dim3(NBLK), dim3(512), 0, stream>>>(X, noise, out, ws);
  router_reduce<<<dim3(32), dim3(704), 0, stream>>>(ws);
  router_final<<<dim3(1), dim3(64), 0, stream>>>(ws, out);
}

// Round 15
// 60.594 us; speedup vs baseline: 1.4605x; 1.2859x over previous
//
#include <hip/hip_runtime.h>
#include <hip/hip_bf16.h>
#include <math.h>

// NoisyTopExpertsPerItemRouter: B=8,S=4096,D=1024,E=64,K=2
#define B_ 8
#define S_ 4096
#define D_ 1024
#define E_ 64
#define NOISE_STD 0.015625f     // max(1/64, 1e-6)
#define INV_NOISE_STD 64.0f
#define OUT_GATES (B_ * S_ * E_)   // 2097152
#define NBLK 1024                  // main grid = S_/4 (32 rows per block)

typedef __attribute__((ext_vector_type(8))) short short8;
typedef __attribute__((ext_vector_type(4))) float f32x4;

// workspace layout (float offsets)
// [0 .. 32768): Wg as bf16 [64][1024] (ushort)
#define WS_GW   32768                    // GW[64]
#define WS_BW   32832                    // BW[64]
#define WS_PART 32896                    // part[1024][644] per-block records
#define PART_STRIDE 644                  // 512 imp + 64 sgn + 64 cnt + c1 + c2
#define WS_TOT  (WS_PART + NBLK * PART_STRIDE)
#define N_TOT   642

// K-loop barrier WITHOUT the vmcnt(0) drain __syncthreads would emit:
// only LDS ordering is needed (staged tile); in-flight global prefetches
// (qx/qb) are consumed via register-use waits and must stay in flight.
#define LDS_BARRIER() \
  asm volatile("s_waitcnt lgkmcnt(0)\n\ts_barrier" ::: "memory")

__device__ __forceinline__ float wave_sum64(float v) {
#pragma unroll
  for (int o = 32; o > 0; o >>= 1) v += __shfl_xor(v, o);
  return v;
}

// ---------------- prep: Wg(bf16) = gamma*W, GW/BW reductions, zero totals ---
__global__ void router_prep(const float* __restrict__ W,
                            const float* __restrict__ gamma,
                            const float* __restrict__ beta,
                            float* __restrict__ ws) {
  if (blockIdx.x >= E_) {
    for (int i = threadIdx.x; i < N_TOT; i += 256) ws[WS_TOT + i] = 0.0f;
    return;
  }
  const int e = blockIdx.x;
  unsigned short* wgb = (unsigned short*)ws;
  float gw = 0.0f, bw = 0.0f;
  for (int d = threadIdx.x; d < D_; d += 256) {
    float wv = W[e * D_ + d];
    float pv = gamma[d] * wv;
    union { __hip_bfloat16 h; unsigned short u; } cv;
    cv.h = __float2bfloat16(pv);
    wgb[e * D_ + d] = cv.u;
    gw += __bfloat162float(cv.h);   // sum of ROUNDED values (consistency)
    bw += beta[d] * wv;
  }
  __shared__ float sred[8];
  gw = wave_sum64(gw);
  bw = wave_sum64(bw);
  const int w = threadIdx.x >> 6, lane = threadIdx.x & 63;
  if (lane == 0) { sred[w] = gw; sred[4 + w] = bw; }
  __syncthreads();
  if (threadIdx.x == 0) {
    ws[WS_GW + e] = sred[0] + sred[1] + sred[2] + sred[3];
    ws[WS_BW + e] = sred[4] + sred[5] + sred[6] + sred[7];
  }
}

// ---------------- main: R9 (60.2us) verbatim + lgkm-only K-loop barriers ----
// block = 512 thr = 8 waves; owns 32 rows (r: b=r&7, sl=r>>3, s=4*bid+sl).
// Wave w: rg=w>>2 (16 rows), et=w&3 (16 experts), FULL K -> acc = 1 f32x4.
// Waves rg=0/1 of same et issue identical B addresses in lockstep (L1 dedup).
// X staged to LDS [row][68]; X reg-queue depth 2 + LDS dbuf; B ring 2 steps
// ahead. K-loop barriers are raw s_barrier + lgkmcnt(0) ONLY -- the global
// prefetch queue is never drained (the R3-R14 per-step stall).
__global__ void __launch_bounds__(512, 4)
router_main(const float* __restrict__ X, const float* __restrict__ noise,
            float* __restrict__ out, float* __restrict__ ws) {
  __shared__ __align__(16) float unbuf[4352];  // 2 x [32][68] staging; -> gcl/gnl
  __shared__ __align__(16) float Lg[2176];     // [32][68] logits; -> pl
  __shared__ float svs[32], sv2s[32];
  __shared__ float cntl[64];
  __shared__ float red8[8];
  float* gcl = unbuf;          // [32][68] clean gates (staging reads done)
  float* gnl = unbuf + 2176;   // [32][68] noisy gates
  float* pl  = Lg;             // per-lane read-then-write -> safe alias

  const int t = threadIdx.x;
  const int w = t >> 6, lane = t & 63;
  const int lrow = lane & 15, kh = lane >> 4;
  const int bid = blockIdx.x;
  const int s0 = bid * 4;

  // staging: thread t -> row r_t = t>>4 (32 rows), cols c_t..c_t+3 of 64-step
  const int r_t = t >> 4, c_t = (t & 15) * 4;
  const int ldso = r_t * 68 + c_t;
  const float* __restrict__ xstage =
      X + ((size_t)(r_t & 7) * S_ + (size_t)(s0 + (r_t >> 3))) * D_ + c_t;

  // GEMM: wave w -> rg = w>>2 (rows 16rg..16rg+15), et = w&3 (experts 16et..)
  const int rg = w >> 2, et = w & 3;
  const unsigned short* __restrict__ bp =
      (const unsigned short*)ws + (16 * et + lrow) * D_ + kh * 8;
  const float gwv = ws[WS_GW + 16 * et + lrow];
  const float bwv = ws[WS_BW + 16 * et + lrow];

  // epilogue indices + EARLY noise load (lands during GEMM)
  const int rr_e = lane >> 4, j_e = lane & 15;
  const int r_e = w * 4 + rr_e;                 // [0,32)
  const int b_e = r_e & 7, sl_e = r_e >> 3;
  const int s_e = s0 + sl_e;
  const float4 nv =
      *(const float4*)(noise + ((size_t)b_e * S_ + s_e) * E_ + 4 * j_e);

  // prologue: X regs for steps 0,1; B ring for steps 0,1; stage step 0
  float4 qx[2];
  short8 qb[2][2];
  qx[0] = *(const float4*)(xstage);
  qx[1] = *(const float4*)(xstage + 64);
  qb[0][0] = *(const short8*)(bp);
  qb[0][1] = *(const short8*)(bp + 32);
  qb[1][0] = *(const short8*)(bp + 64);
  qb[1][1] = *(const short8*)(bp + 96);

  float ssv = 0.0f, ssv2 = 0.0f;
  unbuf[ldso + 0] = qx[0].x; unbuf[ldso + 1] = qx[0].y;
  unbuf[ldso + 2] = qx[0].z; unbuf[ldso + 3] = qx[0].w;
  ssv  += (qx[0].x + qx[0].y) + (qx[0].z + qx[0].w);
  ssv2 = fmaf(qx[0].x, qx[0].x, ssv2); ssv2 = fmaf(qx[0].y, qx[0].y, ssv2);
  ssv2 = fmaf(qx[0].z, qx[0].z, ssv2); ssv2 = fmaf(qx[0].w, qx[0].w, ssv2);

  f32x4 acc = {0.f, 0.f, 0.f, 0.f};

#pragma unroll
  for (int s = 0; s < 16; ++s) {
    LDS_BARRIER();                         // buf[s&1] staged (no vmcnt drain)
    if (s + 2 < 16)                        // X for step s+2 (slot s&1 now free)
      qx[s & 1] = *(const float4*)(xstage + (s + 2) * 64);

    const float* xb = unbuf + (s & 1) * 2176 + (16 * rg + lrow) * 68;
#pragma unroll
    for (int ks = 0; ks < 2; ++ks) {
      float4 a0 = *(const float4*)(xb + ks * 32 + kh * 8);
      float4 a1 = *(const float4*)(xb + ks * 32 + kh * 8 + 4);
      union { short8 s8; __hip_bfloat162 h[4]; } u;
      u.h[0] = __float22bfloat162_rn(make_float2(a0.x, a0.y));
      u.h[1] = __float22bfloat162_rn(make_float2(a0.z, a0.w));
      u.h[2] = __float22bfloat162_rn(make_float2(a1.x, a1.y));
      u.h[3] = __float22bfloat162_rn(make_float2(a1.z, a1.w));
      acc = __builtin_amdgcn_mfma_f32_16x16x32_bf16(u.s8, qb[s & 1][ks],
                                                    acc, 0, 0, 0);
    }
    if (s + 2 < 16) {                      // refill B ring slot just consumed
      qb[s & 1][0] = *(const short8*)(bp + (s + 2) * 64);
      qb[s & 1][1] = *(const short8*)(bp + (s + 2) * 64 + 32);
    }
    if (s + 1 < 16) {                      // stage step s+1 (issued at s-1)
      float4 wv = qx[(s + 1) & 1];
      float* d = unbuf + ((s + 1) & 1) * 2176 + ldso;
      d[0] = wv.x; d[1] = wv.y; d[2] = wv.z; d[3] = wv.w;
      ssv  += (wv.x + wv.y) + (wv.z + wv.w);
      ssv2 = fmaf(wv.x, wv.x, ssv2); ssv2 = fmaf(wv.y, wv.y, ssv2);
      ssv2 = fmaf(wv.z, wv.z, ssv2); ssv2 = fmaf(wv.w, wv.w, ssv2);
    }
  }

  // LN stats: 16 staging threads per row -> shfl reduce within 16-lane group
  ssv  += __shfl_xor(ssv, 1);  ssv  += __shfl_xor(ssv, 2);
  ssv  += __shfl_xor(ssv, 4);  ssv  += __shfl_xor(ssv, 8);
  ssv2 += __shfl_xor(ssv2, 1); ssv2 += __shfl_xor(ssv2, 2);
  ssv2 += __shfl_xor(ssv2, 4); ssv2 += __shfl_xor(ssv2, 8);
  if ((t & 15) == 0) { svs[r_t] = ssv; sv2s[r_t] = ssv2; }
  if (t < 64) cntl[t] = 0.0f;
  __syncthreads();

  // logits: C/D layout col=lane&15, row=(lane>>4)*4+i  [m89-verified]
#pragma unroll
  for (int i = 0; i < 4; i++) {
    const int rloc = 16 * rg + kh * 4 + i;
    const float mui = svs[rloc] * (1.0f / (float)D_);
    const float var = sv2s[rloc] * (1.0f / (float)D_) - mui * mui;
    const float rsi = rsqrtf(var + 1e-5f);
    Lg[rloc * 68 + 16 * et + lrow] = rsi * (acc[i] - mui * gwv) + bwv;
  }
  __syncthreads();   // logits ready; staging reads done -> gcl/gnl reusable

  // ---- epilogue: 8 waves; wave w rows 4w..4w+3; lane=(rr,j), 4 experts ----
  {
    const int r = r_e, b = b_e, s = s_e, j = j_e;
    float4 lv = *(const float4*)(Lg + r * 68 + 4 * j);
    float ln0 = fmaf(NOISE_STD, nv.x, lv.x);
    float ln1 = fmaf(NOISE_STD, nv.y, lv.y);
    float ln2 = fmaf(NOISE_STD, nv.z, lv.z);
    float ln3 = fmaf(NOISE_STD, nv.w, lv.w);

    // combined max+secondmax of noisy logits (m1 also shifts clean softmax)
    float m1 = ln0, m2 = -INFINITY;
    m2 = fmaxf(m2, fminf(m1, ln1)); m1 = fmaxf(m1, ln1);
    m2 = fmaxf(m2, fminf(m1, ln2)); m1 = fmaxf(m1, ln2);
    m2 = fmaxf(m2, fminf(m1, ln3)); m1 = fmaxf(m1, ln3);
#pragma unroll
    for (int o = 1; o <= 8; o <<= 1) {
      float o1 = __shfl_xor(m1, o), o2 = __shfl_xor(m2, o);
      m2 = fmaxf(fmaxf(m2, o2), fminf(m1, o1));
      m1 = fmaxf(m1, o1);
    }
    float ec0 = __expf(lv.x - m1), ec1 = __expf(lv.y - m1);
    float ec2 = __expf(lv.z - m1), ec3 = __expf(lv.w - m1);
    float en0 = __expf(ln0 - m1), en1 = __expf(ln1 - m1);
    float en2 = __expf(ln2 - m1), en3 = __expf(ln3 - m1);
    float sg = (ec0 + ec1) + (ec2 + ec3);
    float sn = (en0 + en1) + (en2 + en3);
#pragma unroll
    for (int o = 1; o <= 8; o <<= 1) {
      sg += __shfl_xor(sg, o);
      sn += __shfl_xor(sn, o);
    }
    const float rg_ = 1.0f / sg, rn_ = 1.0f / sn;
    float4 gnv = { en0 * rn_, en1 * rn_, en2 * rn_, en3 * rn_ };
    float4 gcv = { ec0 * rg_, ec1 * rg_, ec2 * rg_, ec3 * rg_ };
    float z0 = fminf(fmaxf((m2 - lv.x) * INV_NOISE_STD, -10.f), 10.f);
    float z1 = fminf(fmaxf((m2 - lv.y) * INV_NOISE_STD, -10.f), 10.f);
    float z2 = fminf(fmaxf((m2 - lv.z) * INV_NOISE_STD, -10.f), 10.f);
    float z3 = fminf(fmaxf((m2 - lv.w) * INV_NOISE_STD, -10.f), 10.f);
    float4 pv = { 0.5f * (1.0f + erff(z0 * 0.70710678118654752f)),
                  0.5f * (1.0f + erff(z1 * 0.70710678118654752f)),
                  0.5f * (1.0f + erff(z2 * 0.70710678118654752f)),
                  0.5f * (1.0f + erff(z3 * 0.70710678118654752f)) };

    *(float4*)(out + ((size_t)b * S_ + s) * E_ + 4 * j) = gnv;
    *(float4*)(gnl + r * 68 + 4 * j) = gnv;
    *(float4*)(gcl + r * 68 + 4 * j) = gcv;
    *(float4*)(pl  + r * 68 + 4 * j) = pv;
    // top-1 count via equality (ties vanishingly rare; softmax is monotone)
    if (ln0 == m1) atomicAdd(&cntl[4 * j + 0], 1.0f);
    if (ln1 == m1) atomicAdd(&cntl[4 * j + 1], 1.0f);
    if (ln2 == m1) atomicAdd(&cntl[4 * j + 2], 1.0f);
    if (ln3 == m1) atomicAdd(&cntl[4 * j + 3], 1.0f);
  }
  __syncthreads();

  // ---- phase 2: block reductions -> PLAIN per-block record (no atomics) ----
  float* prt = ws + WS_PART + (size_t)bid * PART_STRIDE;
  {
    // importance: thread t -> (b = t>>6, e = t&63), sum over 4 sl
    const int b0i = t >> 6, e0i = t & 63;
    float v = gcl[(0 * 8 + b0i) * 68 + e0i] + gcl[(1 * 8 + b0i) * 68 + e0i] +
              gcl[(2 * 8 + b0i) * 68 + e0i] + gcl[(3 * 8 + b0i) * 68 + e0i];
    prt[t] = v;
  }
  if (t < 64) {
    float sgn = 0.0f;
#pragma unroll
    for (int r = 0; r < 32; r++) sgn += gnl[r * 68 + t];
    prt[512 + t] = sgn;
  } else if (t < 128) {
    prt[576 + (t - 64)] = cntl[t - 64];
  } else if (t < 384) {
    const int idx = t - 128;            // [0,256): sl = idx>>6, e = idx&63
    const int slc = idx >> 6, e = idx & 63;
    float P = 0.0f;
#pragma unroll
    for (int b = 0; b < 8; b++) P += pl[(slc * 8 + b) * 68 + e];
    float c1 = P * 0.125f;
    float c2 = c1 * c1;
    c1 = wave_sum64(c1);
    c2 = wave_sum64(c2);
    if (lane == 0) { red8[(w - 2) * 2] = c1; red8[(w - 2) * 2 + 1] = c2; }
  }
  __syncthreads();
  if (t == 0) {
    prt[640] = (red8[0] + red8[2]) + (red8[4] + red8[6]);
    prt[641] = (red8[1] + red8[3]) + (red8[5] + red8[7]);
  }
}

// ---------------- reduce: 32 blocks x 32 records, deep unroll ---------------
__global__ void router_reduce(float* __restrict__ ws) {
  const int t = threadIdx.x;
  if (t >= N_TOT) return;
  const int base = blockIdx.x * 32;
  const float* p = ws + WS_PART + (size_t)base * PART_STRIDE + t;
  float acc = 0.0f;
#pragma unroll 8
  for (int i = 0; i < 32; ++i) acc += p[(size_t)i * PART_STRIDE];
  atomicAdd(&ws[WS_TOT + t], acc);
}

// ---------------- finalize: 3 scalar losses from totals ---------------------
__global__ void router_final(const float* __restrict__ ws, float* __restrict__ out) {
  const int lane = threadIdx.x;  // 64 threads = 1 wave
  const float* tot = ws + WS_TOT;
  float impsum = 0.0f;
  for (int b = 0; b < B_; ++b) {
    float v = tot[b * 64 + lane];
    float sfull = wave_sum64(v);
    float mean = sfull * (1.0f / 64.0f);
    float d = v - mean;
    float ss = wave_sum64(d * d);
    impsum += (ss / 63.0f) / (mean * mean);
  }
  float importance = impsum * (1.0f / (float)B_);

  const float N = (float)(S_ * E_);
  float meanp = tot[640] / N;
  float varp = tot[641] / N - meanp * meanp;
  float load = varp / (meanp * meanp);

  const float inv_rows = 1.0f / (float)(B_ * S_);
  float te = (tot[576 + lane] * inv_rows) * (tot[512 + lane] * inv_rows);
  float gs = wave_sum64(te) * (float)E_;

  if (lane == 0) {
    out[OUT_GATES + 0] = importance + load;  // aux (GSHARD_W = 0)
    out[OUT_GATES + 1] = gs;
    out[OUT_GATES + 2] = importance;
    out[OUT_GATES + 3] = load;
  }
}

extern "C" void kernel_launch(void* const* d_in, const int* in_sizes, int n_in,
                              void* d_out, int out_size, void* d_ws, size_t ws_size,
                              hipStream_t stream) {
  (void)in_sizes; (void)n_in; (void)out_size; (void)ws_size;
  const float* X     = (const float*)d_in[0];
  const float* noise = (const float*)d_in[1];
  const float* gamma = (const float*)d_in[2];
  const float* beta  = (const float*)d_in[3];
  const float* W     = (const float*)d_in[4];
  float* out = (float*)d_out;
  float* ws  = (float*)d_ws;

  router_prep<<<dim3(E_ + 1), dim3(256), 0, stream>>>(W, gamma, beta, ws);
  router_main<<<dim3(NBLK), dim3(512), 0, stream>>>(X, noise, out, ws);
  router_reduce<<<dim3(32), dim3(704), 0, stream>>>(ws);
  router_final<<<dim3(1), dim3(64), 0, stream>>>(ws, out);
}

// Round 16
// 56.432 us; speedup vs baseline: 1.5682x; 1.0737x over previous
//
#include <hip/hip_runtime.h>
#include <hip/hip_bf16.h>
#include <math.h>

// NoisyTopExpertsPerItemRouter: B=8,S=4096,D=1024,E=64,K=2
#define B_ 8
#define S_ 4096
#define D_ 1024
#define E_ 64
#define NOISE_STD 0.015625f     // max(1/64, 1e-6)
#define INV_NOISE_STD 64.0f
#define OUT_GATES (B_ * S_ * E_)   // 2097152
#define NBLK 1024                  // main grid = S_/4 (32 rows per block)

typedef __attribute__((ext_vector_type(8))) short short8;
typedef __attribute__((ext_vector_type(4))) float f32x4;

// workspace layout (float offsets)
// [0 .. 32768): Wg as bf16 [64][1024] (ushort)
#define WS_GW   32768                    // GW[64]
#define WS_BW   32832                    // BW[64]
#define WS_PART 32896                    // part[1024][644] per-block records
#define PART_STRIDE 644                  // 512 imp + 64 sgn + 64 cnt + c1 + c2
#define WS_TOT  (WS_PART + NBLK * PART_STRIDE)
#define N_TOT   642

// K-loop barrier WITHOUT the vmcnt(0) drain __syncthreads would emit.
#define LDS_BARRIER() \
  asm volatile("s_waitcnt lgkmcnt(0)\n\ts_barrier" ::: "memory")

__device__ __forceinline__ float wave_sum64(float v) {
#pragma unroll
  for (int o = 32; o > 0; o >>= 1) v += __shfl_xor(v, o);
  return v;
}

// ---------------- prep: Wg(bf16) = gamma*W, GW/BW reductions, zero totals ---
__global__ void router_prep(const float* __restrict__ W,
                            const float* __restrict__ gamma,
                            const float* __restrict__ beta,
                            float* __restrict__ ws) {
  if (blockIdx.x >= E_) {
    for (int i = threadIdx.x; i < N_TOT; i += 256) ws[WS_TOT + i] = 0.0f;
    return;
  }
  const int e = blockIdx.x;
  unsigned short* wgb = (unsigned short*)ws;
  float gw = 0.0f, bw = 0.0f;
  for (int d = threadIdx.x; d < D_; d += 256) {
    float wv = W[e * D_ + d];
    float pv = gamma[d] * wv;
    union { __hip_bfloat16 h; unsigned short u; } cv;
    cv.h = __float2bfloat16(pv);
    wgb[e * D_ + d] = cv.u;
    gw += __bfloat162float(cv.h);   // sum of ROUNDED values (consistency)
    bw += beta[d] * wv;
  }
  __shared__ float sred[8];
  gw = wave_sum64(gw);
  bw = wave_sum64(bw);
  const int w = threadIdx.x >> 6, lane = threadIdx.x & 63;
  if (lane == 0) { sred[w] = gw; sred[4 + w] = bw; }
  __syncthreads();
  if (threadIdx.x == 0) {
    ws[WS_GW + e] = sred[0] + sred[1] + sred[2] + sred[3];
    ws[WS_BW + e] = sred[4] + sred[5] + sred[6] + sred[7];
  }
}

// ---------------- main: R15 + XOR-swizzled conflict-free A-tile -------------
// block = 512 thr = 8 waves; owns 32 rows (r: b=r&7, sl=r>>3, s=4*bid+sl).
// Wave w: rg=w>>2 (16 rows), et=w&3 (16 experts), FULL K -> acc = 1 f32x4.
// A-tile LDS layout [32][64] with float4 XOR swizzle:
//   addr_dw = row*64 + ((c4 ^ (row&15))<<2) + (col&3),  c4 = col>>2.
// OLD [row][68] read banks = 4*lrow+8*kh mod 32 -> 8-WAY conflict (2.94x on
// the hottest path). New layout: writes 8 dwords/bank, reads 8 lanes per
// 4-bank group -> conflict-free BOTH sides, 16B-aligned b128 (T2, rule #21).
// Everything else identical to R15 (lgkm-only barrier, queues, epilogue).
__global__ void __launch_bounds__(512, 4)
router_main(const float* __restrict__ X, const float* __restrict__ noise,
            float* __restrict__ out, float* __restrict__ ws) {
  __shared__ __align__(16) float unbuf[4352];  // 2 x [32][64] swz staging; -> gcl/gnl
  __shared__ __align__(16) float Lg[2176];     // [32][68] logits; -> pl
  __shared__ float svs[32], sv2s[32];
  __shared__ float cntl[64];
  __shared__ float red8[8];
  float* gcl = unbuf;          // [32][68] clean gates (staging reads done)
  float* gnl = unbuf + 2176;   // [32][68] noisy gates
  float* pl  = Lg;             // per-lane read-then-write -> safe alias

  const int t = threadIdx.x;
  const int w = t >> 6, lane = t & 63;
  const int lrow = lane & 15, kh = lane >> 4;
  const int bid = blockIdx.x;
  const int s0 = bid * 4;

  // staging: thread t -> row r_t = t>>4 (32 rows), float4 c4w = t&15, swizzled
  const int r_t = t >> 4, c4w = t & 15;
  const int ldso = r_t * 64 + ((c4w ^ (r_t & 15)) << 2);
  const float* __restrict__ xstage =
      X + ((size_t)(r_t & 7) * S_ + (size_t)(s0 + (r_t >> 3))) * D_ + c4w * 4;

  // GEMM: wave w -> rg = w>>2 (rows 16rg..16rg+15), et = w&3 (experts 16et..)
  const int rg = w >> 2, et = w & 3;
  const unsigned short* __restrict__ bp =
      (const unsigned short*)ws + (16 * et + lrow) * D_ + kh * 8;
  const float gwv = ws[WS_GW + 16 * et + lrow];
  const float bwv = ws[WS_BW + 16 * et + lrow];

  // A-read swizzled offsets (row&15 == lrow for row = 16rg+lrow)
  const int arow = 16 * rg + lrow;
  const int abase = arow * 64;
  const int a0_0 = abase + (((0 + 2 * kh + 0) ^ lrow) << 2);   // ks=0, c4, +0
  const int a0_1 = abase + (((0 + 2 * kh + 1) ^ lrow) << 2);   // ks=0, c4+1
  const int a1_0 = abase + (((8 + 2 * kh + 0) ^ lrow) << 2);   // ks=1
  const int a1_1 = abase + (((8 + 2 * kh + 1) ^ lrow) << 2);

  // epilogue indices + EARLY noise load (lands during GEMM)
  const int rr_e = lane >> 4, j_e = lane & 15;
  const int r_e = w * 4 + rr_e;                 // [0,32)
  const int b_e = r_e & 7, sl_e = r_e >> 3;
  const int s_e = s0 + sl_e;
  const float4 nv =
      *(const float4*)(noise + ((size_t)b_e * S_ + s_e) * E_ + 4 * j_e);

  // prologue: X regs for steps 0,1; B ring for steps 0,1; stage step 0
  float4 qx[2];
  short8 qb[2][2];
  qx[0] = *(const float4*)(xstage);
  qx[1] = *(const float4*)(xstage + 64);
  qb[0][0] = *(const short8*)(bp);
  qb[0][1] = *(const short8*)(bp + 32);
  qb[1][0] = *(const short8*)(bp + 64);
  qb[1][1] = *(const short8*)(bp + 96);

  float ssv = 0.0f, ssv2 = 0.0f;
  *(float4*)(&unbuf[ldso]) = qx[0];
  ssv  += (qx[0].x + qx[0].y) + (qx[0].z + qx[0].w);
  ssv2 = fmaf(qx[0].x, qx[0].x, ssv2); ssv2 = fmaf(qx[0].y, qx[0].y, ssv2);
  ssv2 = fmaf(qx[0].z, qx[0].z, ssv2); ssv2 = fmaf(qx[0].w, qx[0].w, ssv2);

  f32x4 acc = {0.f, 0.f, 0.f, 0.f};

#pragma unroll
  for (int s = 0; s < 16; ++s) {
    LDS_BARRIER();                         // buf[s&1] staged (no vmcnt drain)
    if (s + 2 < 16)                        // X for step s+2 (slot s&1 now free)
      qx[s & 1] = *(const float4*)(xstage + (s + 2) * 64);

    const float* xb = unbuf + (s & 1) * 2048;
    {
      float4 a0 = *(const float4*)(xb + a0_0);
      float4 a1 = *(const float4*)(xb + a0_1);
      union { short8 s8; __hip_bfloat162 h[4]; } u;
      u.h[0] = __float22bfloat162_rn(make_float2(a0.x, a0.y));
      u.h[1] = __float22bfloat162_rn(make_float2(a0.z, a0.w));
      u.h[2] = __float22bfloat162_rn(make_float2(a1.x, a1.y));
      u.h[3] = __float22bfloat162_rn(make_float2(a1.z, a1.w));
      acc = __builtin_amdgcn_mfma_f32_16x16x32_bf16(u.s8, qb[s & 1][0],
                                                    acc, 0, 0, 0);
    }
    {
      float4 a0 = *(const float4*)(xb + a1_0);
      float4 a1 = *(const float4*)(xb + a1_1);
      union { short8 s8; __hip_bfloat162 h[4]; } u;
      u.h[0] = __float22bfloat162_rn(make_float2(a0.x, a0.y));
      u.h[1] = __float22bfloat162_rn(make_float2(a0.z, a0.w));
      u.h[2] = __float22bfloat162_rn(make_float2(a1.x, a1.y));
      u.h[3] = __float22bfloat162_rn(make_float2(a1.z, a1.w));
      acc = __builtin_amdgcn_mfma_f32_16x16x32_bf16(u.s8, qb[s & 1][1],
                                                    acc, 0, 0, 0);
    }
    if (s + 2 < 16) {                      // refill B ring slot just consumed
      qb[s & 1][0] = *(const short8*)(bp + (s + 2) * 64);
      qb[s & 1][1] = *(const short8*)(bp + (s + 2) * 64 + 32);
    }
    if (s + 1 < 16) {                      // stage step s+1 (issued at s-1)
      float4 wv = qx[(s + 1) & 1];
      *(float4*)(&unbuf[((s + 1) & 1) * 2048 + ldso]) = wv;
      ssv  += (wv.x + wv.y) + (wv.z + wv.w);
      ssv2 = fmaf(wv.x, wv.x, ssv2); ssv2 = fmaf(wv.y, wv.y, ssv2);
      ssv2 = fmaf(wv.z, wv.z, ssv2); ssv2 = fmaf(wv.w, wv.w, ssv2);
    }
  }

  // LN stats: 16 staging threads per row -> shfl reduce within 16-lane group
  ssv  += __shfl_xor(ssv, 1);  ssv  += __shfl_xor(ssv, 2);
  ssv  += __shfl_xor(ssv, 4);  ssv  += __shfl_xor(ssv, 8);
  ssv2 += __shfl_xor(ssv2, 1); ssv2 += __shfl_xor(ssv2, 2);
  ssv2 += __shfl_xor(ssv2, 4); ssv2 += __shfl_xor(ssv2, 8);
  if ((t & 15) == 0) { svs[r_t] = ssv; sv2s[r_t] = ssv2; }
  if (t < 64) cntl[t] = 0.0f;
  __syncthreads();

  // logits: C/D layout col=lane&15, row=(lane>>4)*4+i  [m89-verified]
#pragma unroll
  for (int i = 0; i < 4; i++) {
    const int rloc = 16 * rg + kh * 4 + i;
    const float mui = svs[rloc] * (1.0f / (float)D_);
    const float var = sv2s[rloc] * (1.0f / (float)D_) - mui * mui;
    const float rsi = rsqrtf(var + 1e-5f);
    Lg[rloc * 68 + 16 * et + lrow] = rsi * (acc[i] - mui * gwv) + bwv;
  }
  __syncthreads();   // logits ready; staging reads done -> gcl/gnl reusable

  // ---- epilogue: 8 waves; wave w rows 4w..4w+3; lane=(rr,j), 4 experts ----
  {
    const int r = r_e, b = b_e, s = s_e, j = j_e;
    float4 lv = *(const float4*)(Lg + r * 68 + 4 * j);
    float ln0 = fmaf(NOISE_STD, nv.x, lv.x);
    float ln1 = fmaf(NOISE_STD, nv.y, lv.y);
    float ln2 = fmaf(NOISE_STD, nv.z, lv.z);
    float ln3 = fmaf(NOISE_STD, nv.w, lv.w);

    // combined max+secondmax of noisy logits (m1 also shifts clean softmax)
    float m1 = ln0, m2 = -INFINITY;
    m2 = fmaxf(m2, fminf(m1, ln1)); m1 = fmaxf(m1, ln1);
    m2 = fmaxf(m2, fminf(m1, ln2)); m1 = fmaxf(m1, ln2);
    m2 = fmaxf(m2, fminf(m1, ln3)); m1 = fmaxf(m1, ln3);
#pragma unroll
    for (int o = 1; o <= 8; o <<= 1) {
      float o1 = __shfl_xor(m1, o), o2 = __shfl_xor(m2, o);
      m2 = fmaxf(fmaxf(m2, o2), fminf(m1, o1));
      m1 = fmaxf(m1, o1);
    }
    float ec0 = __expf(lv.x - m1), ec1 = __expf(lv.y - m1);
    float ec2 = __expf(lv.z - m1), ec3 = __expf(lv.w - m1);
    float en0 = __expf(ln0 - m1), en1 = __expf(ln1 - m1);
    float en2 = __expf(ln2 - m1), en3 = __expf(ln3 - m1);
    float sg = (ec0 + ec1) + (ec2 + ec3);
    float sn = (en0 + en1) + (en2 + en3);
#pragma unroll
    for (int o = 1; o <= 8; o <<= 1) {
      sg += __shfl_xor(sg, o);
      sn += __shfl_xor(sn, o);
    }
    const float rg_ = 1.0f / sg, rn_ = 1.0f / sn;
    float4 gnv = { en0 * rn_, en1 * rn_, en2 * rn_, en3 * rn_ };
    float4 gcv = { ec0 * rg_, ec1 * rg_, ec2 * rg_, ec3 * rg_ };
    float z0 = fminf(fmaxf((m2 - lv.x) * INV_NOISE_STD, -10.f), 10.f);
    float z1 = fminf(fmaxf((m2 - lv.y) * INV_NOISE_STD, -10.f), 10.f);
    float z2 = fminf(fmaxf((m2 - lv.z) * INV_NOISE_STD, -10.f), 10.f);
    float z3 = fminf(fmaxf((m2 - lv.w) * INV_NOISE_STD, -10.f), 10.f);
    float4 pv = { 0.5f * (1.0f + erff(z0 * 0.70710678118654752f)),
                  0.5f * (1.0f + erff(z1 * 0.70710678118654752f)),
                  0.5f * (1.0f + erff(z2 * 0.70710678118654752f)),
                  0.5f * (1.0f + erff(z3 * 0.70710678118654752f)) };

    *(float4*)(out + ((size_t)b * S_ + s) * E_ + 4 * j) = gnv;
    *(float4*)(gnl + r * 68 + 4 * j) = gnv;
    *(float4*)(gcl + r * 68 + 4 * j) = gcv;
    *(float4*)(pl  + r * 68 + 4 * j) = pv;
    // top-1 count via equality (ties vanishingly rare; softmax is monotone)
    if (ln0 == m1) atomicAdd(&cntl[4 * j + 0], 1.0f);
    if (ln1 == m1) atomicAdd(&cntl[4 * j + 1], 1.0f);
    if (ln2 == m1) atomicAdd(&cntl[4 * j + 2], 1.0f);
    if (ln3 == m1) atomicAdd(&cntl[4 * j + 3], 1.0f);
  }
  __syncthreads();

  // ---- phase 2: block reductions -> PLAIN per-block record (no atomics) ----
  float* prt = ws + WS_PART + (size_t)bid * PART_STRIDE;
  {
    // importance: thread t -> (b = t>>6, e = t&63), sum over 4 sl
    const int b0i = t >> 6, e0i = t & 63;
    float v = gcl[(0 * 8 + b0i) * 68 + e0i] + gcl[(1 * 8 + b0i) * 68 + e0i] +
              gcl[(2 * 8 + b0i) * 68 + e0i] + gcl[(3 * 8 + b0i) * 68 + e0i];
    prt[t] = v;
  }
  if (t < 64) {
    float sgn = 0.0f;
#pragma unroll
    for (int r = 0; r < 32; r++) sgn += gnl[r * 68 + t];
    prt[512 + t] = sgn;
  } else if (t < 128) {
    prt[576 + (t - 64)] = cntl[t - 64];
  } else if (t < 384) {
    const int idx = t - 128;            // [0,256): sl = idx>>6, e = idx&63
    const int slc = idx >> 6, e = idx & 63;
    float P = 0.0f;
#pragma unroll
    for (int b = 0; b < 8; b++) P += pl[(slc * 8 + b) * 68 + e];
    float c1 = P * 0.125f;
    float c2 = c1 * c1;
    c1 = wave_sum64(c1);
    c2 = wave_sum64(c2);
    if (lane == 0) { red8[(w - 2) * 2] = c1; red8[(w - 2) * 2 + 1] = c2; }
  }
  __syncthreads();
  if (t == 0) {
    prt[640] = (red8[0] + red8[2]) + (red8[4] + red8[6]);
    prt[641] = (red8[1] + red8[3]) + (red8[5] + red8[7]);
  }
}

// ---------------- reduce: 32 blocks x 32 records, deep unroll ---------------
__global__ void router_reduce(float* __restrict__ ws) {
  const int t = threadIdx.x;
  if (t >= N_TOT) return;
  const int base = blockIdx.x * 32;
  const float* p = ws + WS_PART + (size_t)base * PART_STRIDE + t;
  float acc = 0.0f;
#pragma unroll 8
  for (int i = 0; i < 32; ++i) acc += p[(size_t)i * PART_STRIDE];
  atomicAdd(&ws[WS_TOT + t], acc);
}

// ---------------- finalize: 3 scalar losses from totals ---------------------
__global__ void router_final(const float* __restrict__ ws, float* __restrict__ out) {
  const int lane = threadIdx.x;  // 64 threads = 1 wave
  const float* tot = ws + WS_TOT;
  float impsum = 0.0f;
  for (int b = 0; b < B_; ++b) {
    float v = tot[b * 64 + lane];
    float sfull = wave_sum64(v);
    float mean = sfull * (1.0f / 64.0f);
    float d = v - mean;
    float ss = wave_sum64(d * d);
    impsum += (ss / 63.0f) / (mean * mean);
  }
  float importance = impsum * (1.0f / (float)B_);

  const float N = (float)(S_ * E_);
  float meanp = tot[640] / N;
  float varp = tot[641] / N - meanp * meanp;
  float load = varp / (meanp * meanp);

  const float inv_rows = 1.0f / (float)(B_ * S_);
  float te = (tot[576 + lane] * inv_rows) * (tot[512 + lane] * inv_rows);
  float gs = wave_sum64(te) * (float)E_;

  if (lane == 0) {
    out[OUT_GATES + 0] = importance + load;  // aux (GSHARD_W = 0)
    out[OUT_GATES + 1] = gs;
    out[OUT_GATES + 2] = importance;
    out[OUT_GATES + 3] = load;
  }
}

extern "C" void kernel_launch(void* const* d_in, const int* in_sizes, int n_in,
                              void* d_out, int out_size, void* d_ws, size_t ws_size,
                              hipStream_t stream) {
  (void)in_sizes; (void)n_in; (void)out_size; (void)ws_size;
  const float* X     = (const float*)d_in[0];
  const float* noise = (const float*)d_in[1];
  const float* gamma = (const float*)d_in[2];
  const float* beta  = (const float*)d_in[3];
  const float* W     = (const float*)d_in[4];
  float* out = (float*)d_out;
  float* ws  = (float*)d_ws;

  router_prep<<<dim3(E_ + 1), dim3(256), 0, stream>>>(W, gamma, beta, ws);
  router_main<<<dim3(NBLK), dim3(512), 0, stream>>>(X, noise, out, ws);
  router_reduce<<<dim3(32), dim3(704), 0, stream>>>(ws);
  router_final<<<dim3(1), dim3(64), 0, stream>>>(ws, out);
}